// Round 7
// baseline (418.905 us; speedup 1.0000x reference)
//
#include <hip/hip_runtime.h>
#include <math.h>

#define B_ 2
#define C_ 32
#define D_ 64
#define H_ 128
#define W_ 128
#define N_ (D_*H_*W_)          // 1048576 = 2^20
#define NW_ (N_/64)            // 16384 words per image
#define P_CAP 2048
#define NEG_CAP 12288
#define PAD 5
#define EPS_ 1e-8f
#define SLICES 64
#define TA 4                   // anchors per thread
#define CHUNK 160              // partner rows staged per LDS pass (>= ceil(9680/64))

// ---------------- pack fg bits + W-axis dilation (bitwise) + init ----------------
__global__ __launch_bounds__(256) void k_packW(const int* __restrict__ labels,
                                               unsigned long long* __restrict__ fgbits,
                                               unsigned long long* __restrict__ dilw,
                                               int* cnt_pos, int* cnt_neg,
                                               float* loss_sum, float* acnt, int* done_cnt) {
    if (blockIdx.x == 0) {
        if (threadIdx.x < B_) {
            int t = threadIdx.x;
            cnt_pos[t] = 0; cnt_neg[t] = 0; loss_sum[t] = 0.f; acnt[t] = 0.f;
        }
        if (threadIdx.x == 64) *done_cnt = 0;
    }
    const int lane = threadIdx.x & 63;
    const int w = threadIdx.x >> 6;            // wave id 0..3
    const int word = (blockIdx.x << 2) + w;    // global word index = g>>6
    const int g = blockIdx.x * 256 + threadIdx.x;

    unsigned long long fgw = __ballot(labels[g] > 0);
    __shared__ unsigned long long smem[4];
    if (lane == 0) { fgbits[word] = fgw; smem[w] = fgw; }
    __syncthreads();
    unsigned long long self = smem[w];
    unsigned long long other = smem[w ^ 1];
    unsigned long long out = self;
    if ((word & 1) == 0) {       // low word of the 128-bit W row
#pragma unroll
        for (int k = 1; k <= PAD; ++k)
            out |= (self >> k) | (self << k) | (other << (64 - k));
    } else {                     // high word
#pragma unroll
        for (int k = 1; k <= PAD; ++k)
            out |= (self << k) | (self >> k) | (other >> (64 - k));
    }
    if (lane == 0) dilw[word] = out;
}

// ---------------- fused H+D dilation (121-tap OR) + compact + gather + normalize ----
// grid = B_*D_ blocks; block handles one d-slice = 256 words.
__global__ __launch_bounds__(256) void k_maskCG(const float* __restrict__ features,
                                                const unsigned long long* __restrict__ fgbits,
                                                const unsigned long long* __restrict__ dilw,
                                                int* cnt_pos, int* cnt_neg,
                                                float* __restrict__ pos_feat,
                                                float* __restrict__ neg_feat) {
    const int bd = blockIdx.x;
    const int b = bd >> 6;                   // D_ = 64
    const int d = bd & 63;
    const int tid = threadIdx.x;             // word within slice (h*2 + wp)
    const int h = tid >> 1;

    // phase 1: 2D OR window over dilw == separable H-then-D dilation
    const int qbase = b * NW_ + d * 256;
    const int q = qbase + tid;
    const int dlo = (d >= PAD) ? -PAD : -d;
    const int dhi = (d + PAD <= D_ - 1) ? PAD : (D_ - 1 - d);
    const int hlo = (h >= PAD) ? -PAD : -h;
    const int hhi = (h + PAD <= H_ - 1) ? PAD : (H_ - 1 - h);
    unsigned long long v = 0;
    for (int od = dlo; od <= dhi; ++od)
        for (int oh = hlo; oh <= hhi; ++oh)
            v |= dilw[q + od * 256 + oh * 2];

    __shared__ unsigned long long sDil[256];
    __shared__ unsigned long long sFg[256];
    sFg[tid] = fgbits[q];
    sDil[tid] = v;
    __syncthreads();

    // phase 2: wave w scans words [w*64, w*64+64); wave-aggregated compaction
    const int lane = tid & 63;
    const int w = tid >> 6;
    const unsigned long long ltmask = (lane == 0) ? 0ull : (~0ull >> (64 - lane));
    for (int k = 0; k < 64; ++k) {
        const int widx = w * 64 + k;
        const unsigned long long fgw = sFg[widx];
        const unsigned long long rimw = sDil[widx] & ~fgw;
        if ((fgw | rimw) == 0) continue;     // wave-uniform

        int basep = 0, basen = 0;
        if (lane == 0) {
            if (fgw)  basep = atomicAdd(&cnt_pos[b], __popcll(fgw));
            if (rimw) basen = atomicAdd(&cnt_neg[b], __popcll(rimw));
        }
        basep = __shfl(basep, 0);
        basen = __shfl(basen, 0);

        const bool is_fg = (fgw >> lane) & 1;
        const bool is_rim = (rimw >> lane) & 1;
        if (is_fg || is_rim) {
            const int n = (((d << 8) | widx) << 6) | lane;   // voxel index in image
            int slot; float* dst = nullptr;
            if (is_fg) {
                slot = basep + __popcll(fgw & ltmask);
                if (slot < P_CAP) dst = pos_feat + ((size_t)b * P_CAP + slot) * C_;
            } else {
                slot = basen + __popcll(rimw & ltmask);
                if (slot < NEG_CAP) dst = neg_feat + ((size_t)b * NEG_CAP + slot) * C_;
            }
            if (dst) {
                const float* fbase = features + (size_t)b * C_ * N_ + n;
                float vv[C_];
                float ss = 0.f;
#pragma unroll
                for (int c = 0; c < C_; ++c) {
                    float x = fbase[(size_t)c * N_];
                    vv[c] = x;
                    ss += x * x;
                }
                float inv = 1.0f / fmaxf(sqrtf(ss), 1e-12f);
#pragma unroll
                for (int c = 0; c < C_; ++c) dst[c] = vv[c] * inv;
            }
        }
    }
}

// ---------------- partner-sliced loss, fixed softmax shift m=10 ----------------
// partial layout: [B][SLICES][2][P_CAP]
__device__ __forceinline__ void dot4x(const float4* __restrict__ row4,
                                      const float A[TA][C_], float d[TA]) {
    d[0] = d[1] = d[2] = d[3] = 0.f;
#pragma unroll
    for (int q = 0; q < 8; ++q) {
        float4 v = row4[q];
#pragma unroll
        for (int i = 0; i < TA; ++i) {
            d[i] = fmaf(v.x, A[i][4*q+0], d[i]);
            d[i] = fmaf(v.y, A[i][4*q+1], d[i]);
            d[i] = fmaf(v.z, A[i][4*q+2], d[i]);
            d[i] = fmaf(v.w, A[i][4*q+3], d[i]);
        }
    }
}

__global__ __launch_bounds__(256, 3) void k_loss2(const float* __restrict__ pos_feat,
                                                  const float* __restrict__ neg_feat,
                                                  const int* __restrict__ cnt_pos,
                                                  const int* __restrict__ cnt_neg,
                                                  float* __restrict__ partial) {
    const int slice = blockIdx.x;
    const int tile  = blockIdx.y;
    const int b     = blockIdx.z;
    const int np = min(cnt_pos[b], P_CAP);
    const int nn = min(cnt_neg[b], NEG_CAP);
    const int abase = tile * 256;
    if (abase >= np) return;
    const int total = np + nn;
    const int tid = threadIdx.x;
    const int lane = tid & 63;
    const int w = __builtin_amdgcn_readfirstlane(tid >> 6);

    __shared__ float4 sA4[256 * 8];     // 32 KB anchors (XOR-swizzled), reused as scratch
    __shared__ float4 sP[CHUNK * 8];    // 20 KB partner stage

    // ---- stage anchor tile, XOR-swizzled chunks: slot = r*8 + ((q+r)&7) ----
    {
        const float4* src = (const float4*)(pos_feat + ((size_t)b * P_CAP + abase) * C_);
#pragma unroll
        for (int k = 0; k < 8; ++k) {
            const int idx = tid + k * 256;
            const int r = idx >> 3, q = idx & 7;
            sA4[(r << 3) | ((q + r) & 7)] = src[idx];
        }
    }
    __syncthreads();

    // ---- register fill from LDS: thread owns rows r_i = i*64 + lane (static q) ----
    float A[TA][C_];
#pragma unroll
    for (int i = 0; i < TA; ++i) {
        const int r = i * 64 + lane;
        const int rbase = r << 3;
        const int rot = r & 7;
#pragma unroll
        for (int q = 0; q < 8; ++q) {
            float4 v = sA4[rbase | ((q + rot) & 7)];
            A[i][4*q+0] = v.x; A[i][4*q+1] = v.y; A[i][4*q+2] = v.z; A[i][4*q+3] = v.w;
        }
    }

    float ps[TA] = {0.f, 0.f, 0.f, 0.f};
    float ns[TA] = {0.f, 0.f, 0.f, 0.f};

    const int per = (total + SLICES - 1) / SLICES;
    const int r0 = slice * per;
    const int r1 = min(r0 + per, total);
    const int a1 = abase + lane;                 // anchor i is a1 + 64*i

    const float4* pbase4 = (const float4*)(pos_feat + (size_t)b * P_CAP * C_);
    const float4* nbase4 = (const float4*)(neg_feat + (size_t)b * NEG_CAP * C_);

    for (int c0 = r0; c0 < r1; c0 += CHUNK) {
        const int cnt = min(CHUNK, r1 - c0);
        __syncthreads();
        // coalesced block-wide copy of partner rows into LDS (linear layout)
        for (int idx = tid; idx < cnt * 8; idx += 256) {
            const int r = idx >> 3, q = idx & 7;
            const int gr = c0 + r;
            sP[idx] = (gr < np) ? pbase4[gr * 8 + q] : nbase4[(size_t)(gr - np) * 8 + q];
        }
        __syncthreads();
        // each wave processes rows w, w+4, ... (broadcast ds_read, conflict-free)
#pragma unroll 2
        for (int r = w; r < cnt; r += 4) {
            const int gr = c0 + r;
            float dv[TA];
            dot4x(&sP[r * 8], A, dv);
            if (gr < np) {           // wave-uniform
#pragma unroll
                for (int i = 0; i < TA; ++i) {
                    float e = __expf(fmaf(dv[i], 10.f, -10.f));
                    ps[i] += (gr == a1 + 64 * i) ? 0.f : e;
                }
            } else {
#pragma unroll
                for (int i = 0; i < TA; ++i)
                    ns[i] += __expf(fmaf(dv[i], 10.f, -10.f));
            }
        }
    }

    // ---- cross-wave reduction (reuse sA4 as scratch: [4][256] x 2) ----
    __syncthreads();
    float* redP = (float*)sA4;           // [4][256]
    float* redN = (float*)sA4 + 4 * 256; // [4][256]
#pragma unroll
    for (int i = 0; i < TA; ++i) {
        redP[w * 256 + i * 64 + lane] = ps[i];
        redN[w * 256 + i * 64 + lane] = ns[i];
    }
    __syncthreads();
    {
        float p = redP[0*256 + tid] + redP[1*256 + tid] + redP[2*256 + tid] + redP[3*256 + tid];
        float n = redN[0*256 + tid] + redN[1*256 + tid] + redN[2*256 + tid] + redN[3*256 + tid];
        float* dst = partial + ((size_t)(b * SLICES + slice) * 2) * P_CAP;
        dst[abase + tid] = p;
        dst[P_CAP + abase + tid] = n;
    }
}

// ---------------- per-anchor finalize + last-block scalar output ----------------
#define FIN_BLOCKS (B_ * (P_CAP / 256))   // 16
__global__ __launch_bounds__(256) void k_fin(const float* __restrict__ partial,
                                             const int* __restrict__ cnt_pos,
                                             const int* __restrict__ cnt_neg,
                                             float* __restrict__ loss_sum,
                                             float* __restrict__ acnt,
                                             int* __restrict__ done_cnt,
                                             float* __restrict__ out) {
    const int blocks_per_b = P_CAP / 256;
    const int b = blockIdx.x / blocks_per_b;
    const int a = (blockIdx.x % blocks_per_b) * 256 + threadIdx.x;
    const int np = min(cnt_pos[b], P_CAP);
    const int tid = threadIdx.x;
    float loss = 0.f, cnt = 0.f;
    if (a < np) {
        float num = 0.f, den = 0.f;
        for (int s = 0; s < SLICES; ++s) {
            const float* base = partial + ((size_t)(b * SLICES + s) * 2) * P_CAP;
            num += base[a];
            den += base[P_CAP + a];
        }
        if (num > 0.f) {
            den += num;
            num += EPS_; den += EPS_;
            loss = __logf(den) - __logf(num);
            cnt = 1.f;
        }
    }
    __shared__ float sl[256], sc[256];
    sl[tid] = loss; sc[tid] = cnt;
    __syncthreads();
    for (int off = 128; off > 0; off >>= 1) {
        if (tid < off) { sl[tid] += sl[tid + off]; sc[tid] += sc[tid + off]; }
        __syncthreads();
    }
    if (tid == 0) {
        if (sc[0] > 0.f) {
            atomicAdd(&loss_sum[b], sl[0]);
            atomicAdd(&acnt[b], sc[0]);
        }
        __threadfence();
        int done = atomicAdd(done_cnt, 1);
        if (done == FIN_BLOCKS - 1) {        // last block computes the scalar
            float tot = 0.f, nv = 0.f;
            bool any = false;
            for (int bb = 0; bb < B_; ++bb) {
                float ls = atomicAdd(&loss_sum[bb], 0.f);   // coherent read
                float ac = atomicAdd(&acnt[bb], 0.f);
                bool valid = (cnt_pos[bb] >= 2) && (cnt_neg[bb] > 0) && (ac > 0.f);
                float il = ls / fmaxf(ac, 1.f);
                if (valid) { tot += il; nv += 1.f; any = true; }
            }
            out[0] = any ? tot / fmaxf(nv, 1.f) : 0.f;
        }
    }
}

extern "C" void kernel_launch(void* const* d_in, const int* in_sizes, int n_in,
                              void* d_out, int out_size, void* d_ws, size_t ws_size,
                              hipStream_t stream) {
    const float* features = (const float*)d_in[0];
    const int* labels = (const int*)d_in[1];
    float* out = (float*)d_out;

    // ---- workspace carve ----
    char* p = (char*)d_ws;
    float* pos_feat = (float*)p;                 p += (size_t)B_ * P_CAP * C_ * 4;
    float* neg_feat = (float*)p;                 p += (size_t)B_ * NEG_CAP * C_ * 4;
    float* partial = (float*)p;                  p += (size_t)B_ * SLICES * 2 * P_CAP * 4;
    unsigned long long* fgbits = (unsigned long long*)p;  p += (size_t)B_ * NW_ * 8;
    unsigned long long* dilw = (unsigned long long*)p;    p += (size_t)B_ * NW_ * 8;
    int* cnt_pos = (int*)p;                      p += B_ * 4;
    int* cnt_neg = (int*)p;                      p += B_ * 4;
    float* loss_sum = (float*)p;                 p += B_ * 4;
    float* acnt = (float*)p;                     p += B_ * 4;
    int* done_cnt = (int*)p;                     p += 4;

    const int threads = 256;
    const int vox_blocks = B_ * N_ / threads;          // 8192

    k_packW<<<vox_blocks, threads, 0, stream>>>(labels, fgbits, dilw,
                                                cnt_pos, cnt_neg, loss_sum, acnt, done_cnt);
    k_maskCG<<<B_ * D_, threads, 0, stream>>>(features, fgbits, dilw,
                                              cnt_pos, cnt_neg, pos_feat, neg_feat);
    dim3 lgrid(SLICES, P_CAP / 256, B_);
    k_loss2<<<lgrid, 256, 0, stream>>>(pos_feat, neg_feat, cnt_pos, cnt_neg, partial);
    k_fin<<<FIN_BLOCKS, 256, 0, stream>>>(partial, cnt_pos, cnt_neg,
                                          loss_sum, acnt, done_cnt, out);
}